// Round 3
// baseline (561.745 us; speedup 1.0000x reference)
//
#include <hip/hip_runtime.h>

// DeepKoopmanNoDec — fp32 in/out. R6: (1) scan rewritten as hi/lo bf16 MFMA
// (z=zh+zl, A=Ah+Al prep-split, 3-MFMA fp32 emulation, error ~1e-5/step):
// old scan was LDS-issue-bound (~160us: 64 ds_read_b128/thread/step).
// (2) encoder_tgt: 128-row/1024-thread blocks (16 waves = 8 colgroups x 2
// rowhalves, 128KB hbuf) -> 4 waves/SIMD latency hiding (was 2); cvt_pk
// bf16 packed converts in store_h. (3) zk: 512 thr/block, 1 col/thread.
// Shapes: B=2048, M=64, STATE=32, EMBED=96, LATENT=128, HIDDEN=512.

typedef unsigned short u16;
typedef __attribute__((ext_vector_type(8))) short bf16x8;   // MFMA A/B frag (4 VGPRs)
typedef __attribute__((ext_vector_type(4))) short bf16x4;   // 8B packed store
typedef __attribute__((ext_vector_type(4))) float f32x4;    // MFMA C/D frag

// ws layout (u16 elements unless noted): bf16 frag weights | fp32 z_k | Ah | Al
#define OFF_W1 0              // 32 frags   (K=32 , N=512)
#define OFF_W2 16384          // 512 frags  (K=512, N=512)
#define OFF_W3 278528         // 512 frags
#define OFF_WO 540672         // 96 frags   (K=512, N=96)
#define OFF_ZK_BYTES 1179648  // fp32 z_k: 2048*128 floats (1 MB)
#define OFF_AH 1114112        // u16: 32 frags of A-hi (byte 2228224)
#define OFF_AL 1130496        // u16: 32 frags of A-lo

// d_out regions (float elements): z_pred | x_pred | z_target
#define XPRED_OFF 16777216
#define ZTGT_OFF  20971520

__device__ __forceinline__ float bf2f(u16 u) {
  unsigned int i = ((unsigned int)u) << 16;
  return __builtin_bit_cast(float, i);
}
__device__ __forceinline__ u16 f2bf(float f) {   // round-to-nearest-even
  unsigned int i = __builtin_bit_cast(unsigned int, f);
  i = (i + 0x7FFFu + ((i >> 16) & 1u)) >> 16;
  return (u16)i;
}

// ---------------------------------------------------------------------------
// Prep: swizzle fp32 matrices (row-major K x N) into bf16 B-fragment-linear
// layout. frag f = ct*(K/32)+ks; lane l holds W[ks*32+(l>>4)*8+j][ct*16+(l&15)]
// at u16 offset f*512 + l*8. Frags 1152..1183 = A-hi, 1184..1215 = A-lo
// (lo = f2bf(v - bf2f(f2bf(v))) for the fp32-emulated scan).
// ---------------------------------------------------------------------------
__global__ void prep_swizzle(const float* __restrict__ W1, const float* __restrict__ W2,
                             const float* __restrict__ W3, const float* __restrict__ Wo,
                             const float* __restrict__ Am, u16* __restrict__ dst) {
  int f = blockIdx.x;
  int l = threadIdx.x;
  const float* src; int K, N; u16* d; int lo = 0;
  if (f < 32)        { src = W1; K = 32;  N = 512; d = dst + OFF_W1; }
  else if (f < 544)  { src = W2; K = 512; N = 512; d = dst + OFF_W2; f -= 32; }
  else if (f < 1056) { src = W3; K = 512; N = 512; d = dst + OFF_W3; f -= 544; }
  else if (f < 1152) { src = Wo; K = 512; N = 96;  d = dst + OFF_WO; f -= 1056; }
  else if (f < 1184) { src = Am; K = 128; N = 128; d = dst + OFF_AH; f -= 1152; }
  else               { src = Am; K = 128; N = 128; d = dst + OFF_AL; f -= 1184; lo = 1; }
  const int KF = K >> 5;
  const int ct = f / KF, ks = f - ct * KF;
  const int q = l >> 4, n = l & 15;
  const int kbase = ks * 32 + q * 8;
  const int col = ct * 16 + n;
  bf16x8 vh;
  #pragma unroll
  for (int j = 0; j < 8; ++j) {
    float v = src[(size_t)(kbase + j) * N + col];
    u16 h = f2bf(v);
    if (lo) h = f2bf(v - bf2f(h));
    vh[j] = (short)h;
  }
  *(bf16x8*)(d + ((size_t)f * 64 + l) * 8) = vh;
}

// ---------------------------------------------------------------------------
// encoder_tgt. hbuf: row-major [128][512] bf16, XOR swizzle on u16 index:
// idx = (row*512 + k) ^ ((row&7)<<3). 16 waves = 8 colgroups x 2 rowhalves;
// each wave: 64 rows x 64 cols, acc[4][4]. Weights global->VGPR (L2/L1;
// rowhalf pair of waves shares each b-frag -> L1 hit).
// ---------------------------------------------------------------------------
__device__ __forceinline__ void store_h(const f32x4 (&acc)[4][4],
                                        const float* __restrict__ bias,
                                        u16* hbuf, int rh, int cg, int q, int n) {
  __syncthreads();                       // all readers of previous h done
  #pragma unroll
  for (int i = 0; i < 4; ++i) {
    const int col = cg * 64 + i * 16 + n;
    const float bia = bias[col];
    #pragma unroll
    for (int rg = 0; rg < 4; ++rg) {
      const int rb = rh * 64 + rg * 16 + q * 4;   // C layout: col=lane&15, row=(lane>>4)*4+r
      float f0 = fmaxf(acc[rg][i][0] + bia, 0.f);
      float f1 = fmaxf(acc[rg][i][1] + bia, 0.f);
      float f2 = fmaxf(acc[rg][i][2] + bia, 0.f);
      float f3 = fmaxf(acc[rg][i][3] + bia, 0.f);
      unsigned p01, p23;
      asm("v_cvt_pk_bf16_f32 %0, %1, %2" : "=v"(p01) : "v"(f0), "v"(f1));
      asm("v_cvt_pk_bf16_f32 %0, %1, %2" : "=v"(p23) : "v"(f2), "v"(f3));
      hbuf[((rb + 0) * 512 + col) ^ (((rb + 0) & 7) << 3)] = (u16)(p01 & 0xFFFFu);
      hbuf[((rb + 1) * 512 + col) ^ (((rb + 1) & 7) << 3)] = (u16)(p01 >> 16);
      hbuf[((rb + 2) * 512 + col) ^ (((rb + 2) & 7) << 3)] = (u16)(p23 & 0xFFFFu);
      hbuf[((rb + 3) * 512 + col) ^ (((rb + 3) & 7) << 3)] = (u16)(p23 >> 16);
    }
  }
  __syncthreads();                       // new h visible to all waves
}

__device__ __forceinline__ void big_layer(const u16* __restrict__ wb,
                                          const float* __restrict__ bias,
                                          u16* hbuf, int rh, int cg, int l, int q, int n) {
  f32x4 acc[4][4];
  #pragma unroll
  for (int rg = 0; rg < 4; ++rg)
    #pragma unroll
    for (int i = 0; i < 4; ++i) acc[rg][i] = (f32x4){0.f, 0.f, 0.f, 0.f};
  #pragma unroll 2
  for (int ks = 0; ks < 16; ++ks) {
    bf16x8 b[4], a[4];
    #pragma unroll
    for (int i = 0; i < 4; ++i)
      b[i] = *(const bf16x8*)(wb + (size_t)((4 * cg + i) * 16 + ks) * 512 + (size_t)l * 8);
    #pragma unroll
    for (int rg = 0; rg < 4; ++rg) {
      const int row = rh * 64 + rg * 16 + n;   // A layout: row=lane&15, k=(lane>>4)*8+j
      a[rg] = *(const bf16x8*)&hbuf[(row * 512 + ks * 32 + q * 8) ^ ((row & 7) << 3)];
    }
    #pragma unroll
    for (int rg = 0; rg < 4; ++rg)
      #pragma unroll
      for (int i = 0; i < 4; ++i)
        acc[rg][i] = __builtin_amdgcn_mfma_f32_16x16x32_bf16(a[rg], b[i], acc[rg][i], 0, 0, 0);
  }
  store_h(acc, bias, hbuf, rh, cg, q, n);
}

__global__ __launch_bounds__(1024, 4) void encoder_tgt(
    const float* __restrict__ xnext, const u16* __restrict__ wf,
    const float* __restrict__ b1, const float* __restrict__ b2,
    const float* __restrict__ b3, const float* __restrict__ bo_,
    float* __restrict__ ztgt) {
  __shared__ __align__(16) u16 hbuf[128 * 512];   // 128KB, swizzled
  const int tid = threadIdx.x;
  const int wv = tid >> 6, l = tid & 63;
  const int q = l >> 4, n = l & 15;
  const int rh = wv >> 3, cg = wv & 7;
  const size_t row0 = (size_t)blockIdx.x * 128;

  // stage x -> hbuf (bf16) + exact fp32 pass-through to ztgt cols 0..31
  {
    const int r = tid >> 3, k0 = (tid & 7) * 4;
    f32x4 x = *(const f32x4*)(xnext + (row0 + r) * 32 + k0);
    *(f32x4*)(ztgt + (row0 + r) * 128 + k0) = x;
    bf16x4 v;
    #pragma unroll
    for (int j = 0; j < 4; ++j) v[j] = (short)f2bf(x[j]);
    *(bf16x4*)&hbuf[(r * 512 + k0) ^ ((r & 7) << 3)] = v;
  }
  __syncthreads();

  // ---- layer 1 (K=32, single ks-chunk) ----
  {
    f32x4 acc[4][4];
    #pragma unroll
    for (int rg = 0; rg < 4; ++rg)
      #pragma unroll
      for (int i = 0; i < 4; ++i) acc[rg][i] = (f32x4){0.f, 0.f, 0.f, 0.f};
    bf16x8 a[4];
    #pragma unroll
    for (int rg = 0; rg < 4; ++rg) {
      const int row = rh * 64 + rg * 16 + n;
      a[rg] = *(const bf16x8*)&hbuf[(row * 512 + q * 8) ^ ((row & 7) << 3)];
    }
    #pragma unroll
    for (int i = 0; i < 4; ++i) {
      bf16x8 b = *(const bf16x8*)(wf + OFF_W1 + (size_t)(4 * cg + i) * 512 + (size_t)l * 8);
      #pragma unroll
      for (int rg = 0; rg < 4; ++rg)
        acc[rg][i] = __builtin_amdgcn_mfma_f32_16x16x32_bf16(a[rg], b, acc[rg][i], 0, 0, 0);
    }
    store_h(acc, b1, hbuf, rh, cg, q, n);
  }

  // ---- layers 2, 3 ----
  big_layer(wf + OFF_W2, b2, hbuf, rh, cg, l, q, n);
  big_layer(wf + OFF_W3, b3, hbuf, rh, cg, l, q, n);

  // ---- output layer: 6 col-tiles, colgroups 0..5 (both rowhalves) ----
  if (cg < 6) {
    f32x4 o[4];
    #pragma unroll
    for (int rg = 0; rg < 4; ++rg) o[rg] = (f32x4){0.f, 0.f, 0.f, 0.f};
    #pragma unroll 2
    for (int ks = 0; ks < 16; ++ks) {
      bf16x8 b = *(const bf16x8*)(wf + OFF_WO + (size_t)(cg * 16 + ks) * 512 + (size_t)l * 8);
      #pragma unroll
      for (int rg = 0; rg < 4; ++rg) {
        const int row = rh * 64 + rg * 16 + n;
        bf16x8 a = *(const bf16x8*)&hbuf[(row * 512 + ks * 32 + q * 8) ^ ((row & 7) << 3)];
        o[rg] = __builtin_amdgcn_mfma_f32_16x16x32_bf16(a, b, o[rg], 0, 0, 0);
      }
    }
    const float bia = bo_[cg * 16 + n];
    #pragma unroll
    for (int rg = 0; rg < 4; ++rg)
      #pragma unroll
      for (int r = 0; r < 4; ++r)
        ztgt[(row0 + rh * 64 + rg * 16 + q * 4 + r) * 128 + 32 + cg * 16 + n] = o[rg][r] + bia;
  }
}

// ---------------------------------------------------------------------------
// z_k encoder — exact fp32 VALU. R6: 512 threads (1 col/thread, 8 rows).
// ---------------------------------------------------------------------------
__global__ __launch_bounds__(512) void encoder_zk_f32(
    const float* __restrict__ xk,
    const float* __restrict__ W1, const float* __restrict__ b1,
    const float* __restrict__ W2, const float* __restrict__ b2,
    const float* __restrict__ W3, const float* __restrict__ b3,
    const float* __restrict__ Wo, const float* __restrict__ bo_,
    float* __restrict__ zk_out) {
  __shared__ __align__(16) float hb[2][8][512];
  __shared__ __align__(16) float xb[8][32];
  const int t = threadIdx.x;
  const int row0 = blockIdx.x * 8;
  if (t < 256) {
    int r = t >> 5, j = t & 31;
    float v = xk[(size_t)(row0 + r) * 32 + j];
    xb[r][j] = v;
    zk_out[(size_t)(row0 + r) * 128 + j] = v;      // x pass-through
  }
  __syncthreads();
  const int c = t;
  // layer 1: K=32
  {
    float a[8];
    const float i0 = b1[c];
    #pragma unroll
    for (int r = 0; r < 8; ++r) a[r] = i0;
    for (int k = 0; k < 32; k += 4) {
      float w0 = W1[(size_t)(k+0)*512 + c];
      float w1 = W1[(size_t)(k+1)*512 + c];
      float w2 = W1[(size_t)(k+2)*512 + c];
      float w3 = W1[(size_t)(k+3)*512 + c];
      #pragma unroll
      for (int r = 0; r < 8; ++r) {
        f32x4 z = *(const f32x4*)&xb[r][k];
        a[r] += z[0]*w0 + z[1]*w1 + z[2]*w2 + z[3]*w3;
      }
    }
    #pragma unroll
    for (int r = 0; r < 8; ++r) hb[0][r][c] = fmaxf(a[r], 0.f);
  }
  __syncthreads();
  // layers 2,3: K=512
  #pragma unroll
  for (int lyr = 0; lyr < 2; ++lyr) {
    const float* W = lyr ? W3 : W2;
    const float* bb = lyr ? b3 : b2;
    const float (*hin)[512] = hb[lyr & 1];
    float (*hout)[512] = hb[(lyr & 1) ^ 1];
    float a[8];
    const float i0 = bb[c];
    #pragma unroll
    for (int r = 0; r < 8; ++r) a[r] = i0;
    for (int k = 0; k < 512; k += 4) {
      float w0 = W[(size_t)(k+0)*512 + c];
      float w1 = W[(size_t)(k+1)*512 + c];
      float w2 = W[(size_t)(k+2)*512 + c];
      float w3 = W[(size_t)(k+3)*512 + c];
      #pragma unroll
      for (int r = 0; r < 8; ++r) {
        f32x4 z = *(const f32x4*)&hin[r][k];
        a[r] += z[0]*w0 + z[1]*w1 + z[2]*w2 + z[3]*w3;
      }
    }
    #pragma unroll
    for (int r = 0; r < 8; ++r) hout[r][c] = fmaxf(a[r], 0.f);
    __syncthreads();
  }
  // output layer: N=96
  if (t < 96) {
    float a[8];
    const float i0 = bo_[t];
    #pragma unroll
    for (int r = 0; r < 8; ++r) a[r] = i0;
    for (int k = 0; k < 512; k += 4) {
      float w0 = Wo[(size_t)(k+0)*96 + t];
      float w1 = Wo[(size_t)(k+1)*96 + t];
      float w2 = Wo[(size_t)(k+2)*96 + t];
      float w3 = Wo[(size_t)(k+3)*96 + t];
      #pragma unroll
      for (int r = 0; r < 8; ++r) {
        f32x4 z = *(const f32x4*)&hb[0][r][k];
        a[r] += z[0]*w0 + z[1]*w1 + z[2]*w2 + z[3]*w3;
      }
    }
    #pragma unroll
    for (int r = 0; r < 8; ++r)
      zk_out[(size_t)(row0 + r) * 128 + 32 + t] = a[r];
  }
}

// ---------------------------------------------------------------------------
// Scan — hi/lo bf16 MFMA (fp32 emulation): z_{s+1} = z_s @ A + u_s @ Bmat.
// Block = 8 rows, 256 thr (4 waves, 2 coltiles each). Ah/Al staged in LDS
// (64KB). Per step: conv (z -> zh/zl bf16, bu = u@B) | barrier | 24 MFMA
// (zh@Ah + zl@Ah + zh@Al per ct/ks) | epilogue (acc+bu -> zbuf, zpred) |
// barrier. Error ~1e-5/step (bf16 x bf16 products exact in fp32).
// ---------------------------------------------------------------------------
__global__ __launch_bounds__(256) void scan_mfma(
    const float* __restrict__ zk, const u16* __restrict__ wf,
    const float* __restrict__ Bm, const float* __restrict__ useq,
    float* __restrict__ zpred, float* __restrict__ xpred) {
  __shared__ __align__(16) u16 ahf[32 * 512];     // 32KB A-hi frags
  __shared__ __align__(16) u16 alf[32 * 512];     // 32KB A-lo frags
  __shared__ __align__(16) float ubuf[8 * 512];   // 16KB u (rows x steps x 8)
  __shared__ __align__(16) float zbuf[8][132];    // current z (fp32, padded)
  __shared__ __align__(16) u16 zh[16][136];       // z hi bf16 (padded)
  __shared__ __align__(16) u16 zl[16][136];       // z lo bf16
  __shared__ __align__(16) float bu[8][132];      // u@B for this step
  const int t = threadIdx.x;
  const int wv = t >> 6, l = t & 63;
  const int q = l >> 4, n = l & 15;
  const size_t b0 = (size_t)blockIdx.x * 8;

  // async stage Ah/Al (wave wv: frags wv*8 .. wv*8+8)
  #pragma unroll
  for (int i = 0; i < 8; ++i) {
    const int f = wv * 8 + i;
    __builtin_amdgcn_global_load_lds(
        (const __attribute__((address_space(1))) unsigned int*)(wf + OFF_AH + (size_t)f * 512 + l * 8),
        (__attribute__((address_space(3))) unsigned int*)(ahf + (size_t)f * 512), 16, 0, 0);
    __builtin_amdgcn_global_load_lds(
        (const __attribute__((address_space(1))) unsigned int*)(wf + OFF_AL + (size_t)f * 512 + l * 8),
        (__attribute__((address_space(3))) unsigned int*)(alf + (size_t)f * 512), 16, 0, 0);
  }
  // stage u (16KB contiguous: useq[b0.., :, :] is linear)
  {
    const float* us = useq + b0 * 512;
    #pragma unroll
    for (int i = 0; i < 4; ++i)
      *(f32x4*)&ubuf[i * 1024 + t * 4] = *(const f32x4*)(us + i * 1024 + t * 4);
  }
  // z0; zero the garbage rows 8..15 of zh/zl (MFMA reads them)
  const int crow = t >> 5, cc0 = (t & 31) * 4;
  *(f32x4*)&zbuf[crow][cc0] = *(const f32x4*)(zk + (b0 + crow) * 128 + cc0);
  for (int i = t; i < 8 * 136; i += 256) { (&zh[8][0])[i] = 0; (&zl[8][0])[i] = 0; }
  // B columns for bu (loop-invariant, 32 VGPR)
  f32x4 bmr[8];
  #pragma unroll
  for (int j = 0; j < 8; ++j) bmr[j] = *(const f32x4*)(Bm + (size_t)j * 128 + cc0);
  __syncthreads();

  const int ct0 = 2 * wv, ct1 = 2 * wv + 1;
  for (int s = 0; s < 64; ++s) {
    // ---- conv + bu (thread: row=crow, cols cc0..cc0+4) ----
    {
      f32x4 z = *(const f32x4*)&zbuf[crow][cc0];
      bf16x4 vh, vl;
      #pragma unroll
      for (int i = 0; i < 4; ++i) {
        u16 h = f2bf(z[i]);
        vh[i] = (short)h;
        vl[i] = (short)f2bf(z[i] - bf2f(h));
      }
      *(bf16x4*)&zh[crow][cc0] = vh;
      *(bf16x4*)&zl[crow][cc0] = vl;
      f32x4 uu0 = *(const f32x4*)&ubuf[crow * 512 + s * 8];
      f32x4 uu1 = *(const f32x4*)&ubuf[crow * 512 + s * 8 + 4];
      f32x4 bv = uu0[0] * bmr[0];
      bv += uu0[1] * bmr[1]; bv += uu0[2] * bmr[2]; bv += uu0[3] * bmr[3];
      bv += uu1[0] * bmr[4]; bv += uu1[1] * bmr[5]; bv += uu1[2] * bmr[6]; bv += uu1[3] * bmr[7];
      *(f32x4*)&bu[crow][cc0] = bv;
    }
    __syncthreads();
    // ---- MFMA: wave wv computes out-cols [wv*32, wv*32+32) ----
    f32x4 acc0 = {0.f, 0.f, 0.f, 0.f};
    f32x4 acc1 = {0.f, 0.f, 0.f, 0.f};
    #pragma unroll
    for (int ks = 0; ks < 4; ++ks) {
      const int ko = ks * 32 + q * 8;
      bf16x8 azh = *(const bf16x8*)&zh[n][ko];     // A: row=lane&15, k=(lane>>4)*8+j
      bf16x8 azl = *(const bf16x8*)&zl[n][ko];
      bf16x8 bh0 = *(const bf16x8*)&ahf[(size_t)(ct0 * 4 + ks) * 512 + l * 8];
      bf16x8 bl0 = *(const bf16x8*)&alf[(size_t)(ct0 * 4 + ks) * 512 + l * 8];
      bf16x8 bh1 = *(const bf16x8*)&ahf[(size_t)(ct1 * 4 + ks) * 512 + l * 8];
      bf16x8 bl1 = *(const bf16x8*)&alf[(size_t)(ct1 * 4 + ks) * 512 + l * 8];
      acc0 = __builtin_amdgcn_mfma_f32_16x16x32_bf16(azh, bh0, acc0, 0, 0, 0);
      acc0 = __builtin_amdgcn_mfma_f32_16x16x32_bf16(azl, bh0, acc0, 0, 0, 0);
      acc0 = __builtin_amdgcn_mfma_f32_16x16x32_bf16(azh, bl0, acc0, 0, 0, 0);
      acc1 = __builtin_amdgcn_mfma_f32_16x16x32_bf16(azh, bh1, acc1, 0, 0, 0);
      acc1 = __builtin_amdgcn_mfma_f32_16x16x32_bf16(azl, bh1, acc1, 0, 0, 0);
      acc1 = __builtin_amdgcn_mfma_f32_16x16x32_bf16(azh, bl1, acc1, 0, 0, 0);
    }
    // ---- epilogue: rows 0..7 live in q<2 lanes (C: col=lane&15, row=q*4+r)
    if (q < 2) {
      #pragma unroll
      for (int r = 0; r < 4; ++r) {
        const int row = q * 4 + r;
        const int c0 = ct0 * 16 + n, c1 = ct1 * 16 + n;
        const float v0 = acc0[r] + bu[row][c0];
        const float v1 = acc1[r] + bu[row][c1];
        zbuf[row][c0] = v0;
        zbuf[row][c1] = v1;
        const size_t go = (b0 + row) * 64 + s;
        zpred[go * 128 + c0] = v0;
        zpred[go * 128 + c1] = v1;
        if (wv == 0) {                 // cols 0..31 = x_pred
          xpred[go * 32 + c0] = v0;
          xpred[go * 32 + c1] = v1;
        }
      }
    }
    __syncthreads();
  }
}

// ---------------------------------------------------------------------------
extern "C" void kernel_launch(void* const* d_in, const int* in_sizes, int n_in,
                              void* d_out, int out_size, void* d_ws, size_t ws_size,
                              hipStream_t stream) {
  (void)in_sizes; (void)n_in; (void)out_size; (void)ws_size;
  const float* xk    = (const float*)d_in[0];
  const float* useq  = (const float*)d_in[1];
  const float* xnext = (const float*)d_in[2];
  const float* W1 = (const float*)d_in[3];
  const float* b1 = (const float*)d_in[4];
  const float* W2 = (const float*)d_in[5];
  const float* b2 = (const float*)d_in[6];
  const float* W3 = (const float*)d_in[7];
  const float* b3 = (const float*)d_in[8];
  const float* Wo = (const float*)d_in[9];
  const float* bo = (const float*)d_in[10];
  const float* A  = (const float*)d_in[11];
  const float* Bm = (const float*)d_in[12];

  float* out   = (float*)d_out;
  float* zpred = out;
  float* xpred = out + XPRED_OFF;
  float* ztgt  = out + ZTGT_OFF;
  u16*   wf    = (u16*)d_ws;
  float* zkw   = (float*)((char*)d_ws + OFF_ZK_BYTES);

  prep_swizzle<<<1216, 64, 0, stream>>>(W1, W2, W3, Wo, A, wf);
  encoder_zk_f32<<<256, 512, 0, stream>>>(xk, W1, b1, W2, b2, W3, b3, Wo, bo, zkw);
  scan_mfma<<<256, 256, 0, stream>>>(zkw, wf, Bm, useq, zpred, xpred);
  encoder_tgt<<<1024, 1024, 0, stream>>>(xnext, wf, b1, b2, b3, bo, ztgt);
}

// Round 4
// 559.768 us; speedup vs baseline: 1.0035x; 1.0035x over previous
//
#include <hip/hip_runtime.h>

// DeepKoopmanNoDec — fp32 in/out. R7: single fix over R6 — encoder_tgt
// __launch_bounds__(1024, 4) made hipcc cap VGPRs at 64 (8-wave/SIMD
// budget) and spill ~190MB each way (FETCH 165MB / WRITE 258MB, VGPR=64).
// Dropping the min-occupancy arg restores the ~96-VGPR clean compile while
// keeping the 128-row / 16-wave / 4-waves-per-SIMD structure (occupancy
// 43.6% confirmed in R6). scan = hi/lo bf16 MFMA emulation (R6), zk = fp32
// VALU 512thr (R6), prep unchanged.
// Shapes: B=2048, M=64, STATE=32, EMBED=96, LATENT=128, HIDDEN=512.

typedef unsigned short u16;
typedef __attribute__((ext_vector_type(8))) short bf16x8;   // MFMA A/B frag (4 VGPRs)
typedef __attribute__((ext_vector_type(4))) short bf16x4;   // 8B packed store
typedef __attribute__((ext_vector_type(4))) float f32x4;    // MFMA C/D frag

// ws layout (u16 elements unless noted): bf16 frag weights | fp32 z_k | Ah | Al
#define OFF_W1 0              // 32 frags   (K=32 , N=512)
#define OFF_W2 16384          // 512 frags  (K=512, N=512)
#define OFF_W3 278528         // 512 frags
#define OFF_WO 540672         // 96 frags   (K=512, N=96)
#define OFF_ZK_BYTES 1179648  // fp32 z_k: 2048*128 floats (1 MB)
#define OFF_AH 1114112        // u16: 32 frags of A-hi
#define OFF_AL 1130496        // u16: 32 frags of A-lo

// d_out regions (float elements): z_pred | x_pred | z_target
#define XPRED_OFF 16777216
#define ZTGT_OFF  20971520

__device__ __forceinline__ float bf2f(u16 u) {
  unsigned int i = ((unsigned int)u) << 16;
  return __builtin_bit_cast(float, i);
}
__device__ __forceinline__ u16 f2bf(float f) {   // round-to-nearest-even
  unsigned int i = __builtin_bit_cast(unsigned int, f);
  i = (i + 0x7FFFu + ((i >> 16) & 1u)) >> 16;
  return (u16)i;
}

// ---------------------------------------------------------------------------
// Prep: swizzle fp32 matrices (row-major K x N) into bf16 B-fragment-linear
// layout. frag f = ct*(K/32)+ks; lane l holds W[ks*32+(l>>4)*8+j][ct*16+(l&15)]
// at u16 offset f*512 + l*8. Frags 1152..1183 = A-hi, 1184..1215 = A-lo
// (lo = f2bf(v - bf2f(f2bf(v))) for the fp32-emulated scan).
// ---------------------------------------------------------------------------
__global__ void prep_swizzle(const float* __restrict__ W1, const float* __restrict__ W2,
                             const float* __restrict__ W3, const float* __restrict__ Wo,
                             const float* __restrict__ Am, u16* __restrict__ dst) {
  int f = blockIdx.x;
  int l = threadIdx.x;
  const float* src; int K, N; u16* d; int lo = 0;
  if (f < 32)        { src = W1; K = 32;  N = 512; d = dst + OFF_W1; }
  else if (f < 544)  { src = W2; K = 512; N = 512; d = dst + OFF_W2; f -= 32; }
  else if (f < 1056) { src = W3; K = 512; N = 512; d = dst + OFF_W3; f -= 544; }
  else if (f < 1152) { src = Wo; K = 512; N = 96;  d = dst + OFF_WO; f -= 1056; }
  else if (f < 1184) { src = Am; K = 128; N = 128; d = dst + OFF_AH; f -= 1152; }
  else               { src = Am; K = 128; N = 128; d = dst + OFF_AL; f -= 1184; lo = 1; }
  const int KF = K >> 5;
  const int ct = f / KF, ks = f - ct * KF;
  const int q = l >> 4, n = l & 15;
  const int kbase = ks * 32 + q * 8;
  const int col = ct * 16 + n;
  bf16x8 vh;
  #pragma unroll
  for (int j = 0; j < 8; ++j) {
    float v = src[(size_t)(kbase + j) * N + col];
    u16 h = f2bf(v);
    if (lo) h = f2bf(v - bf2f(h));
    vh[j] = (short)h;
  }
  *(bf16x8*)(d + ((size_t)f * 64 + l) * 8) = vh;
}

// ---------------------------------------------------------------------------
// encoder_tgt. hbuf: row-major [128][512] bf16, XOR swizzle on u16 index:
// idx = (row*512 + k) ^ ((row&7)<<3). 16 waves = 8 colgroups x 2 rowhalves;
// each wave: 64 rows x 64 cols, acc[4][4]. Weights global->VGPR (L2/L1).
// ---------------------------------------------------------------------------
__device__ __forceinline__ void store_h(const f32x4 (&acc)[4][4],
                                        const float* __restrict__ bias,
                                        u16* hbuf, int rh, int cg, int q, int n) {
  __syncthreads();                       // all readers of previous h done
  #pragma unroll
  for (int i = 0; i < 4; ++i) {
    const int col = cg * 64 + i * 16 + n;
    const float bia = bias[col];
    #pragma unroll
    for (int rg = 0; rg < 4; ++rg) {
      const int rb = rh * 64 + rg * 16 + q * 4;   // C layout: col=lane&15, row=(lane>>4)*4+r
      float f0 = fmaxf(acc[rg][i][0] + bia, 0.f);
      float f1 = fmaxf(acc[rg][i][1] + bia, 0.f);
      float f2 = fmaxf(acc[rg][i][2] + bia, 0.f);
      float f3 = fmaxf(acc[rg][i][3] + bia, 0.f);
      unsigned p01, p23;
      asm("v_cvt_pk_bf16_f32 %0, %1, %2" : "=v"(p01) : "v"(f0), "v"(f1));
      asm("v_cvt_pk_bf16_f32 %0, %1, %2" : "=v"(p23) : "v"(f2), "v"(f3));
      hbuf[((rb + 0) * 512 + col) ^ (((rb + 0) & 7) << 3)] = (u16)(p01 & 0xFFFFu);
      hbuf[((rb + 1) * 512 + col) ^ (((rb + 1) & 7) << 3)] = (u16)(p01 >> 16);
      hbuf[((rb + 2) * 512 + col) ^ (((rb + 2) & 7) << 3)] = (u16)(p23 & 0xFFFFu);
      hbuf[((rb + 3) * 512 + col) ^ (((rb + 3) & 7) << 3)] = (u16)(p23 >> 16);
    }
  }
  __syncthreads();                       // new h visible to all waves
}

__device__ __forceinline__ void big_layer(const u16* __restrict__ wb,
                                          const float* __restrict__ bias,
                                          u16* hbuf, int rh, int cg, int l, int q, int n) {
  f32x4 acc[4][4];
  #pragma unroll
  for (int rg = 0; rg < 4; ++rg)
    #pragma unroll
    for (int i = 0; i < 4; ++i) acc[rg][i] = (f32x4){0.f, 0.f, 0.f, 0.f};
  #pragma unroll 2
  for (int ks = 0; ks < 16; ++ks) {
    bf16x8 b[4], a[4];
    #pragma unroll
    for (int i = 0; i < 4; ++i)
      b[i] = *(const bf16x8*)(wb + (size_t)((4 * cg + i) * 16 + ks) * 512 + (size_t)l * 8);
    #pragma unroll
    for (int rg = 0; rg < 4; ++rg) {
      const int row = rh * 64 + rg * 16 + n;   // A layout: row=lane&15, k=(lane>>4)*8+j
      a[rg] = *(const bf16x8*)&hbuf[(row * 512 + ks * 32 + q * 8) ^ ((row & 7) << 3)];
    }
    #pragma unroll
    for (int rg = 0; rg < 4; ++rg)
      #pragma unroll
      for (int i = 0; i < 4; ++i)
        acc[rg][i] = __builtin_amdgcn_mfma_f32_16x16x32_bf16(a[rg], b[i], acc[rg][i], 0, 0, 0);
  }
  store_h(acc, bias, hbuf, rh, cg, q, n);
}

__global__ __launch_bounds__(1024) void encoder_tgt(
    const float* __restrict__ xnext, const u16* __restrict__ wf,
    const float* __restrict__ b1, const float* __restrict__ b2,
    const float* __restrict__ b3, const float* __restrict__ bo_,
    float* __restrict__ ztgt) {
  __shared__ __align__(16) u16 hbuf[128 * 512];   // 128KB, swizzled
  const int tid = threadIdx.x;
  const int wv = tid >> 6, l = tid & 63;
  const int q = l >> 4, n = l & 15;
  const int rh = wv >> 3, cg = wv & 7;
  const size_t row0 = (size_t)blockIdx.x * 128;

  // stage x -> hbuf (bf16) + exact fp32 pass-through to ztgt cols 0..31
  {
    const int r = tid >> 3, k0 = (tid & 7) * 4;
    f32x4 x = *(const f32x4*)(xnext + (row0 + r) * 32 + k0);
    *(f32x4*)(ztgt + (row0 + r) * 128 + k0) = x;
    bf16x4 v;
    #pragma unroll
    for (int j = 0; j < 4; ++j) v[j] = (short)f2bf(x[j]);
    *(bf16x4*)&hbuf[(r * 512 + k0) ^ ((r & 7) << 3)] = v;
  }
  __syncthreads();

  // ---- layer 1 (K=32, single ks-chunk) ----
  {
    f32x4 acc[4][4];
    #pragma unroll
    for (int rg = 0; rg < 4; ++rg)
      #pragma unroll
      for (int i = 0; i < 4; ++i) acc[rg][i] = (f32x4){0.f, 0.f, 0.f, 0.f};
    bf16x8 a[4];
    #pragma unroll
    for (int rg = 0; rg < 4; ++rg) {
      const int row = rh * 64 + rg * 16 + n;
      a[rg] = *(const bf16x8*)&hbuf[(row * 512 + q * 8) ^ ((row & 7) << 3)];
    }
    #pragma unroll
    for (int i = 0; i < 4; ++i) {
      bf16x8 b = *(const bf16x8*)(wf + OFF_W1 + (size_t)(4 * cg + i) * 512 + (size_t)l * 8);
      #pragma unroll
      for (int rg = 0; rg < 4; ++rg)
        acc[rg][i] = __builtin_amdgcn_mfma_f32_16x16x32_bf16(a[rg], b, acc[rg][i], 0, 0, 0);
    }
    store_h(acc, b1, hbuf, rh, cg, q, n);
  }

  // ---- layers 2, 3 ----
  big_layer(wf + OFF_W2, b2, hbuf, rh, cg, l, q, n);
  big_layer(wf + OFF_W3, b3, hbuf, rh, cg, l, q, n);

  // ---- output layer: 6 col-tiles, colgroups 0..5 (both rowhalves) ----
  if (cg < 6) {
    f32x4 o[4];
    #pragma unroll
    for (int rg = 0; rg < 4; ++rg) o[rg] = (f32x4){0.f, 0.f, 0.f, 0.f};
    #pragma unroll 2
    for (int ks = 0; ks < 16; ++ks) {
      bf16x8 b = *(const bf16x8*)(wf + OFF_WO + (size_t)(cg * 16 + ks) * 512 + (size_t)l * 8);
      #pragma unroll
      for (int rg = 0; rg < 4; ++rg) {
        const int row = rh * 64 + rg * 16 + n;
        bf16x8 a = *(const bf16x8*)&hbuf[(row * 512 + ks * 32 + q * 8) ^ ((row & 7) << 3)];
        o[rg] = __builtin_amdgcn_mfma_f32_16x16x32_bf16(a, b, o[rg], 0, 0, 0);
      }
    }
    const float bia = bo_[cg * 16 + n];
    #pragma unroll
    for (int rg = 0; rg < 4; ++rg)
      #pragma unroll
      for (int r = 0; r < 4; ++r)
        ztgt[(row0 + rh * 64 + rg * 16 + q * 4 + r) * 128 + 32 + cg * 16 + n] = o[rg][r] + bia;
  }
}

// ---------------------------------------------------------------------------
// z_k encoder — exact fp32 VALU. 512 threads (1 col/thread, 8 rows).
// ---------------------------------------------------------------------------
__global__ __launch_bounds__(512) void encoder_zk_f32(
    const float* __restrict__ xk,
    const float* __restrict__ W1, const float* __restrict__ b1,
    const float* __restrict__ W2, const float* __restrict__ b2,
    const float* __restrict__ W3, const float* __restrict__ b3,
    const float* __restrict__ Wo, const float* __restrict__ bo_,
    float* __restrict__ zk_out) {
  __shared__ __align__(16) float hb[2][8][512];
  __shared__ __align__(16) float xb[8][32];
  const int t = threadIdx.x;
  const int row0 = blockIdx.x * 8;
  if (t < 256) {
    int r = t >> 5, j = t & 31;
    float v = xk[(size_t)(row0 + r) * 32 + j];
    xb[r][j] = v;
    zk_out[(size_t)(row0 + r) * 128 + j] = v;      // x pass-through
  }
  __syncthreads();
  const int c = t;
  // layer 1: K=32
  {
    float a[8];
    const float i0 = b1[c];
    #pragma unroll
    for (int r = 0; r < 8; ++r) a[r] = i0;
    for (int k = 0; k < 32; k += 4) {
      float w0 = W1[(size_t)(k+0)*512 + c];
      float w1 = W1[(size_t)(k+1)*512 + c];
      float w2 = W1[(size_t)(k+2)*512 + c];
      float w3 = W1[(size_t)(k+3)*512 + c];
      #pragma unroll
      for (int r = 0; r < 8; ++r) {
        f32x4 z = *(const f32x4*)&xb[r][k];
        a[r] += z[0]*w0 + z[1]*w1 + z[2]*w2 + z[3]*w3;
      }
    }
    #pragma unroll
    for (int r = 0; r < 8; ++r) hb[0][r][c] = fmaxf(a[r], 0.f);
  }
  __syncthreads();
  // layers 2,3: K=512
  #pragma unroll
  for (int lyr = 0; lyr < 2; ++lyr) {
    const float* W = lyr ? W3 : W2;
    const float* bb = lyr ? b3 : b2;
    const float (*hin)[512] = hb[lyr & 1];
    float (*hout)[512] = hb[(lyr & 1) ^ 1];
    float a[8];
    const float i0 = bb[c];
    #pragma unroll
    for (int r = 0; r < 8; ++r) a[r] = i0;
    for (int k = 0; k < 512; k += 4) {
      float w0 = W[(size_t)(k+0)*512 + c];
      float w1 = W[(size_t)(k+1)*512 + c];
      float w2 = W[(size_t)(k+2)*512 + c];
      float w3 = W[(size_t)(k+3)*512 + c];
      #pragma unroll
      for (int r = 0; r < 8; ++r) {
        f32x4 z = *(const f32x4*)&hin[r][k];
        a[r] += z[0]*w0 + z[1]*w1 + z[2]*w2 + z[3]*w3;
      }
    }
    #pragma unroll
    for (int r = 0; r < 8; ++r) hout[r][c] = fmaxf(a[r], 0.f);
    __syncthreads();
  }
  // output layer: N=96
  if (t < 96) {
    float a[8];
    const float i0 = bo_[t];
    #pragma unroll
    for (int r = 0; r < 8; ++r) a[r] = i0;
    for (int k = 0; k < 512; k += 4) {
      float w0 = Wo[(size_t)(k+0)*96 + t];
      float w1 = Wo[(size_t)(k+1)*96 + t];
      float w2 = Wo[(size_t)(k+2)*96 + t];
      float w3 = Wo[(size_t)(k+3)*96 + t];
      #pragma unroll
      for (int r = 0; r < 8; ++r) {
        f32x4 z = *(const f32x4*)&hb[0][r][k];
        a[r] += z[0]*w0 + z[1]*w1 + z[2]*w2 + z[3]*w3;
      }
    }
    #pragma unroll
    for (int r = 0; r < 8; ++r)
      zk_out[(size_t)(row0 + r) * 128 + 32 + t] = a[r];
  }
}

// ---------------------------------------------------------------------------
// Scan — hi/lo bf16 MFMA (fp32 emulation): z_{s+1} = z_s @ A + u_s @ Bmat.
// Block = 8 rows, 256 thr (4 waves, 2 coltiles each). Ah/Al staged in LDS.
// Error ~1e-5/step (bf16 x bf16 products exact in fp32).
// ---------------------------------------------------------------------------
__global__ __launch_bounds__(256) void scan_mfma(
    const float* __restrict__ zk, const u16* __restrict__ wf,
    const float* __restrict__ Bm, const float* __restrict__ useq,
    float* __restrict__ zpred, float* __restrict__ xpred) {
  __shared__ __align__(16) u16 ahf[32 * 512];     // 32KB A-hi frags
  __shared__ __align__(16) u16 alf[32 * 512];     // 32KB A-lo frags
  __shared__ __align__(16) float ubuf[8 * 512];   // 16KB u (rows x steps x 8)
  __shared__ __align__(16) float zbuf[8][132];    // current z (fp32, padded)
  __shared__ __align__(16) u16 zh[16][136];       // z hi bf16 (padded)
  __shared__ __align__(16) u16 zl[16][136];       // z lo bf16
  __shared__ __align__(16) float bu[8][132];      // u@B for this step
  const int t = threadIdx.x;
  const int wv = t >> 6, l = t & 63;
  const int q = l >> 4, n = l & 15;
  const size_t b0 = (size_t)blockIdx.x * 8;

  // async stage Ah/Al (wave wv: frags wv*8 .. wv*8+8)
  #pragma unroll
  for (int i = 0; i < 8; ++i) {
    const int f = wv * 8 + i;
    __builtin_amdgcn_global_load_lds(
        (const __attribute__((address_space(1))) unsigned int*)(wf + OFF_AH + (size_t)f * 512 + l * 8),
        (__attribute__((address_space(3))) unsigned int*)(ahf + (size_t)f * 512), 16, 0, 0);
    __builtin_amdgcn_global_load_lds(
        (const __attribute__((address_space(1))) unsigned int*)(wf + OFF_AL + (size_t)f * 512 + l * 8),
        (__attribute__((address_space(3))) unsigned int*)(alf + (size_t)f * 512), 16, 0, 0);
  }
  // stage u (16KB contiguous: useq[b0.., :, :] is linear)
  {
    const float* us = useq + b0 * 512;
    #pragma unroll
    for (int i = 0; i < 4; ++i)
      *(f32x4*)&ubuf[i * 1024 + t * 4] = *(const f32x4*)(us + i * 1024 + t * 4);
  }
  // z0; zero the garbage rows 8..15 of zh/zl (MFMA reads them)
  const int crow = t >> 5, cc0 = (t & 31) * 4;
  *(f32x4*)&zbuf[crow][cc0] = *(const f32x4*)(zk + (b0 + crow) * 128 + cc0);
  for (int i = t; i < 8 * 136; i += 256) { (&zh[8][0])[i] = 0; (&zl[8][0])[i] = 0; }
  // B columns for bu (loop-invariant, 32 VGPR)
  f32x4 bmr[8];
  #pragma unroll
  for (int j = 0; j < 8; ++j) bmr[j] = *(const f32x4*)(Bm + (size_t)j * 128 + cc0);
  __syncthreads();

  const int ct0 = 2 * wv, ct1 = 2 * wv + 1;
  for (int s = 0; s < 64; ++s) {
    // ---- conv + bu (thread: row=crow, cols cc0..cc0+4) ----
    {
      f32x4 z = *(const f32x4*)&zbuf[crow][cc0];
      bf16x4 vh, vl;
      #pragma unroll
      for (int i = 0; i < 4; ++i) {
        u16 h = f2bf(z[i]);
        vh[i] = (short)h;
        vl[i] = (short)f2bf(z[i] - bf2f(h));
      }
      *(bf16x4*)&zh[crow][cc0] = vh;
      *(bf16x4*)&zl[crow][cc0] = vl;
      f32x4 uu0 = *(const f32x4*)&ubuf[crow * 512 + s * 8];
      f32x4 uu1 = *(const f32x4*)&ubuf[crow * 512 + s * 8 + 4];
      f32x4 bv = uu0[0] * bmr[0];
      bv += uu0[1] * bmr[1]; bv += uu0[2] * bmr[2]; bv += uu0[3] * bmr[3];
      bv += uu1[0] * bmr[4]; bv += uu1[1] * bmr[5]; bv += uu1[2] * bmr[6]; bv += uu1[3] * bmr[7];
      *(f32x4*)&bu[crow][cc0] = bv;
    }
    __syncthreads();
    // ---- MFMA: wave wv computes out-cols [wv*32, wv*32+32) ----
    f32x4 acc0 = {0.f, 0.f, 0.f, 0.f};
    f32x4 acc1 = {0.f, 0.f, 0.f, 0.f};
    #pragma unroll
    for (int ks = 0; ks < 4; ++ks) {
      const int ko = ks * 32 + q * 8;
      bf16x8 azh = *(const bf16x8*)&zh[n][ko];     // A: row=lane&15, k=(lane>>4)*8+j
      bf16x8 azl = *(const bf16x8*)&zl[n][ko];
      bf16x8 bh0 = *(const bf16x8*)&ahf[(size_t)(ct0 * 4 + ks) * 512 + l * 8];
      bf16x8 bl0 = *(const bf16x8*)&alf[(size_t)(ct0 * 4 + ks) * 512 + l * 8];
      bf16x8 bh1 = *(const bf16x8*)&ahf[(size_t)(ct1 * 4 + ks) * 512 + l * 8];
      bf16x8 bl1 = *(const bf16x8*)&alf[(size_t)(ct1 * 4 + ks) * 512 + l * 8];
      acc0 = __builtin_amdgcn_mfma_f32_16x16x32_bf16(azh, bh0, acc0, 0, 0, 0);
      acc0 = __builtin_amdgcn_mfma_f32_16x16x32_bf16(azl, bh0, acc0, 0, 0, 0);
      acc0 = __builtin_amdgcn_mfma_f32_16x16x32_bf16(azh, bl0, acc0, 0, 0, 0);
      acc1 = __builtin_amdgcn_mfma_f32_16x16x32_bf16(azh, bh1, acc1, 0, 0, 0);
      acc1 = __builtin_amdgcn_mfma_f32_16x16x32_bf16(azl, bh1, acc1, 0, 0, 0);
      acc1 = __builtin_amdgcn_mfma_f32_16x16x32_bf16(azh, bl1, acc1, 0, 0, 0);
    }
    // ---- epilogue: rows 0..7 live in q<2 lanes (C: col=lane&15, row=q*4+r)
    if (q < 2) {
      #pragma unroll
      for (int r = 0; r < 4; ++r) {
        const int row = q * 4 + r;
        const int c0 = ct0 * 16 + n, c1 = ct1 * 16 + n;
        const float v0 = acc0[r] + bu[row][c0];
        const float v1 = acc1[r] + bu[row][c1];
        zbuf[row][c0] = v0;
        zbuf[row][c1] = v1;
        const size_t go = (b0 + row) * 64 + s;
        zpred[go * 128 + c0] = v0;
        zpred[go * 128 + c1] = v1;
        if (wv == 0) {                 // cols 0..31 = x_pred
          xpred[go * 32 + c0] = v0;
          xpred[go * 32 + c1] = v1;
        }
      }
    }
    __syncthreads();
  }
}

// ---------------------------------------------------------------------------
extern "C" void kernel_launch(void* const* d_in, const int* in_sizes, int n_in,
                              void* d_out, int out_size, void* d_ws, size_t ws_size,
                              hipStream_t stream) {
  (void)in_sizes; (void)n_in; (void)out_size; (void)ws_size;
  const float* xk    = (const float*)d_in[0];
  const float* useq  = (const float*)d_in[1];
  const float* xnext = (const float*)d_in[2];
  const float* W1 = (const float*)d_in[3];
  const float* b1 = (const float*)d_in[4];
  const float* W2 = (const float*)d_in[5];
  const float* b2 = (const float*)d_in[6];
  const float* W3 = (const float*)d_in[7];
  const float* b3 = (const float*)d_in[8];
  const float* Wo = (const float*)d_in[9];
  const float* bo = (const float*)d_in[10];
  const float* A  = (const float*)d_in[11];
  const float* Bm = (const float*)d_in[12];

  float* out   = (float*)d_out;
  float* zpred = out;
  float* xpred = out + XPRED_OFF;
  float* ztgt  = out + ZTGT_OFF;
  u16*   wf    = (u16*)d_ws;
  float* zkw   = (float*)((char*)d_ws + OFF_ZK_BYTES);

  prep_swizzle<<<1216, 64, 0, stream>>>(W1, W2, W3, Wo, A, wf);
  encoder_zk_f32<<<256, 512, 0, stream>>>(xk, W1, b1, W2, b2, W3, b3, Wo, bo, zkw);
  scan_mfma<<<256, 256, 0, stream>>>(zkw, wf, Bm, useq, zpred, xpred);
  encoder_tgt<<<1024, 1024, 0, stream>>>(xnext, wf, b1, b2, b3, bo, ztgt);
}

// Round 5
// 522.516 us; speedup vs baseline: 1.0751x; 1.0713x over previous
//
#include <hip/hip_runtime.h>

// DeepKoopmanNoDec — fp32 in/out. R8: 1024-thr blocks pin VGPR budget at 64
// (R6/R7: spill regardless of launch_bounds 2nd arg) -> back to 512-thr
// blocks, which empirically compile clean ((512,2) cap=256 VGPR). encoder:
// 8 waves = 2 rowhalves x 4 colgroups, acc[4][8] (64x128/wave) — halves LDS
// A-traffic vs R5's acc[4][4] and gives 32 independent MFMAs per ks chunk;
// 128-row blocks (1024 total) halve L2 weight traffic vs R5. scan: 512 thr
// (2 waves/SIMD, was 1) + 3 independent MFMA partial chains (len 4, was one
// len-12 chain). zk/prep unchanged.
// Shapes: B=2048, M=64, STATE=32, EMBED=96, LATENT=128, HIDDEN=512.

typedef unsigned short u16;
typedef __attribute__((ext_vector_type(8))) short bf16x8;   // MFMA A/B frag (4 VGPRs)
typedef __attribute__((ext_vector_type(4))) short bf16x4;   // 8B packed store
typedef __attribute__((ext_vector_type(4))) float f32x4;    // MFMA C/D frag

// ws layout (u16 elements unless noted): bf16 frag weights | fp32 z_k | Ah | Al
#define OFF_W1 0              // 32 frags   (K=32 , N=512)
#define OFF_W2 16384          // 512 frags  (K=512, N=512)
#define OFF_W3 278528         // 512 frags
#define OFF_WO 540672         // 96 frags   (K=512, N=96)
#define OFF_ZK_BYTES 1179648  // fp32 z_k: 2048*128 floats (1 MB)
#define OFF_AH 1114112        // u16: 32 frags of A-hi
#define OFF_AL 1130496        // u16: 32 frags of A-lo

// d_out regions (float elements): z_pred | x_pred | z_target
#define XPRED_OFF 16777216
#define ZTGT_OFF  20971520

__device__ __forceinline__ float bf2f(u16 u) {
  unsigned int i = ((unsigned int)u) << 16;
  return __builtin_bit_cast(float, i);
}
__device__ __forceinline__ u16 f2bf(float f) {   // round-to-nearest-even
  unsigned int i = __builtin_bit_cast(unsigned int, f);
  i = (i + 0x7FFFu + ((i >> 16) & 1u)) >> 16;
  return (u16)i;
}

// ---------------------------------------------------------------------------
// Prep: swizzle fp32 matrices (row-major K x N) into bf16 B-fragment-linear
// layout. frag f = ct*(K/32)+ks; lane l holds W[ks*32+(l>>4)*8+j][ct*16+(l&15)]
// at u16 offset f*512 + l*8. Frags 1152..1183 = A-hi, 1184..1215 = A-lo.
// ---------------------------------------------------------------------------
__global__ void prep_swizzle(const float* __restrict__ W1, const float* __restrict__ W2,
                             const float* __restrict__ W3, const float* __restrict__ Wo,
                             const float* __restrict__ Am, u16* __restrict__ dst) {
  int f = blockIdx.x;
  int l = threadIdx.x;
  const float* src; int K, N; u16* d; int lo = 0;
  if (f < 32)        { src = W1; K = 32;  N = 512; d = dst + OFF_W1; }
  else if (f < 544)  { src = W2; K = 512; N = 512; d = dst + OFF_W2; f -= 32; }
  else if (f < 1056) { src = W3; K = 512; N = 512; d = dst + OFF_W3; f -= 544; }
  else if (f < 1152) { src = Wo; K = 512; N = 96;  d = dst + OFF_WO; f -= 1056; }
  else if (f < 1184) { src = Am; K = 128; N = 128; d = dst + OFF_AH; f -= 1152; }
  else               { src = Am; K = 128; N = 128; d = dst + OFF_AL; f -= 1184; lo = 1; }
  const int KF = K >> 5;
  const int ct = f / KF, ks = f - ct * KF;
  const int q = l >> 4, n = l & 15;
  const int kbase = ks * 32 + q * 8;
  const int col = ct * 16 + n;
  bf16x8 vh;
  #pragma unroll
  for (int j = 0; j < 8; ++j) {
    float v = src[(size_t)(kbase + j) * N + col];
    u16 h = f2bf(v);
    if (lo) h = f2bf(v - bf2f(h));
    vh[j] = (short)h;
  }
  *(bf16x8*)(d + ((size_t)f * 64 + l) * 8) = vh;
}

// ---------------------------------------------------------------------------
// encoder_tgt. hbuf: row-major [128][512] bf16, XOR swizzle on u16 index:
// idx = (row*512 + k) ^ ((row&7)<<3). 8 waves = 2 rowhalves x 4 colgroups;
// wave tile 64 rows x 128 cols, acc[4][8] (~230 VGPR, cap 256 via (512,2)).
// Weights global->VGPR (L2/L1; rowhalf pair shares each b-frag -> L1 hit).
// ---------------------------------------------------------------------------
__device__ __forceinline__ void store_h(const f32x4 (&acc)[4][8],
                                        const float* __restrict__ bias,
                                        u16* hbuf, int rh, int cg, int q, int n) {
  __syncthreads();                       // all readers of previous h done
  #pragma unroll
  for (int i = 0; i < 8; ++i) {
    const int col = cg * 128 + i * 16 + n;
    const float bia = bias[col];
    #pragma unroll
    for (int rg = 0; rg < 4; ++rg) {
      const int rb = rh * 64 + rg * 16 + q * 4;   // C layout: col=lane&15, row=(lane>>4)*4+r
      float f0 = fmaxf(acc[rg][i][0] + bia, 0.f);
      float f1 = fmaxf(acc[rg][i][1] + bia, 0.f);
      float f2 = fmaxf(acc[rg][i][2] + bia, 0.f);
      float f3 = fmaxf(acc[rg][i][3] + bia, 0.f);
      unsigned p01, p23;
      asm("v_cvt_pk_bf16_f32 %0, %1, %2" : "=v"(p01) : "v"(f0), "v"(f1));
      asm("v_cvt_pk_bf16_f32 %0, %1, %2" : "=v"(p23) : "v"(f2), "v"(f3));
      hbuf[((rb + 0) * 512 + col) ^ (((rb + 0) & 7) << 3)] = (u16)(p01 & 0xFFFFu);
      hbuf[((rb + 1) * 512 + col) ^ (((rb + 1) & 7) << 3)] = (u16)(p01 >> 16);
      hbuf[((rb + 2) * 512 + col) ^ (((rb + 2) & 7) << 3)] = (u16)(p23 & 0xFFFFu);
      hbuf[((rb + 3) * 512 + col) ^ (((rb + 3) & 7) << 3)] = (u16)(p23 >> 16);
    }
  }
  __syncthreads();                       // new h visible to all waves
}

__device__ __forceinline__ void big_layer(const u16* __restrict__ wb,
                                          const float* __restrict__ bias,
                                          u16* hbuf, int rh, int cg, int l, int q, int n) {
  f32x4 acc[4][8];
  #pragma unroll
  for (int rg = 0; rg < 4; ++rg)
    #pragma unroll
    for (int i = 0; i < 8; ++i) acc[rg][i] = (f32x4){0.f, 0.f, 0.f, 0.f};
  #pragma unroll 2
  for (int ks = 0; ks < 16; ++ks) {
    bf16x8 b[8], a[4];
    #pragma unroll
    for (int i = 0; i < 8; ++i)
      b[i] = *(const bf16x8*)(wb + (size_t)((8 * cg + i) * 16 + ks) * 512 + (size_t)l * 8);
    #pragma unroll
    for (int rg = 0; rg < 4; ++rg) {
      const int row = rh * 64 + rg * 16 + n;   // A layout: row=lane&15, k=(lane>>4)*8+j
      a[rg] = *(const bf16x8*)&hbuf[(row * 512 + ks * 32 + q * 8) ^ ((row & 7) << 3)];
    }
    #pragma unroll
    for (int rg = 0; rg < 4; ++rg)
      #pragma unroll
      for (int i = 0; i < 8; ++i)
        acc[rg][i] = __builtin_amdgcn_mfma_f32_16x16x32_bf16(a[rg], b[i], acc[rg][i], 0, 0, 0);
  }
  store_h(acc, bias, hbuf, rh, cg, q, n);
}

__global__ __launch_bounds__(512, 2) void encoder_tgt(
    const float* __restrict__ xnext, const u16* __restrict__ wf,
    const float* __restrict__ b1, const float* __restrict__ b2,
    const float* __restrict__ b3, const float* __restrict__ bo_,
    float* __restrict__ ztgt) {
  __shared__ __align__(16) u16 hbuf[128 * 512];   // 128KB, swizzled
  const int tid = threadIdx.x;
  const int wv = tid >> 6, l = tid & 63;
  const int q = l >> 4, n = l & 15;
  const int rh = wv >> 2, cg = wv & 3;
  const size_t row0 = (size_t)blockIdx.x * 128;

  // stage x -> hbuf (bf16) + exact fp32 pass-through to ztgt cols 0..31
  {
    const int r = tid >> 2, k0 = (tid & 3) * 8;
    f32x4 x0 = *(const f32x4*)(xnext + (row0 + r) * 32 + k0);
    f32x4 x1 = *(const f32x4*)(xnext + (row0 + r) * 32 + k0 + 4);
    *(f32x4*)(ztgt + (row0 + r) * 128 + k0)     = x0;
    *(f32x4*)(ztgt + (row0 + r) * 128 + k0 + 4) = x1;
    bf16x8 v;
    #pragma unroll
    for (int j = 0; j < 4; ++j) { v[j] = (short)f2bf(x0[j]); v[4 + j] = (short)f2bf(x1[j]); }
    *(bf16x8*)&hbuf[(r * 512 + k0) ^ ((r & 7) << 3)] = v;
  }
  __syncthreads();

  // ---- layer 1 (K=32, single ks-chunk) ----
  {
    f32x4 acc[4][8];
    #pragma unroll
    for (int rg = 0; rg < 4; ++rg)
      #pragma unroll
      for (int i = 0; i < 8; ++i) acc[rg][i] = (f32x4){0.f, 0.f, 0.f, 0.f};
    bf16x8 a[4];
    #pragma unroll
    for (int rg = 0; rg < 4; ++rg) {
      const int row = rh * 64 + rg * 16 + n;
      a[rg] = *(const bf16x8*)&hbuf[(row * 512 + q * 8) ^ ((row & 7) << 3)];
    }
    #pragma unroll
    for (int i = 0; i < 8; ++i) {
      bf16x8 b = *(const bf16x8*)(wf + OFF_W1 + (size_t)(8 * cg + i) * 512 + (size_t)l * 8);
      #pragma unroll
      for (int rg = 0; rg < 4; ++rg)
        acc[rg][i] = __builtin_amdgcn_mfma_f32_16x16x32_bf16(a[rg], b, acc[rg][i], 0, 0, 0);
    }
    store_h(acc, b1, hbuf, rh, cg, q, n);
  }

  // ---- layers 2, 3 ----
  big_layer(wf + OFF_W2, b2, hbuf, rh, cg, l, q, n);
  big_layer(wf + OFF_W3, b3, hbuf, rh, cg, l, q, n);

  // ---- output layer: 6 col-tiles, waves 0..5 one tile each, all 128 rows ----
  if (wv < 6) {
    f32x4 o[8];
    #pragma unroll
    for (int rg = 0; rg < 8; ++rg) o[rg] = (f32x4){0.f, 0.f, 0.f, 0.f};
    #pragma unroll 2
    for (int ks = 0; ks < 16; ++ks) {
      bf16x8 b = *(const bf16x8*)(wf + OFF_WO + (size_t)(wv * 16 + ks) * 512 + (size_t)l * 8);
      #pragma unroll
      for (int rg = 0; rg < 8; ++rg) {
        const int row = rg * 16 + n;
        bf16x8 a = *(const bf16x8*)&hbuf[(row * 512 + ks * 32 + q * 8) ^ ((row & 7) << 3)];
        o[rg] = __builtin_amdgcn_mfma_f32_16x16x32_bf16(a, b, o[rg], 0, 0, 0);
      }
    }
    const float bia = bo_[wv * 16 + n];
    #pragma unroll
    for (int rg = 0; rg < 8; ++rg)
      #pragma unroll
      for (int r = 0; r < 4; ++r)
        ztgt[(row0 + rg * 16 + q * 4 + r) * 128 + 32 + wv * 16 + n] = o[rg][r] + bia;
  }
}

// ---------------------------------------------------------------------------
// z_k encoder — exact fp32 VALU. 512 threads (1 col/thread, 8 rows).
// ---------------------------------------------------------------------------
__global__ __launch_bounds__(512) void encoder_zk_f32(
    const float* __restrict__ xk,
    const float* __restrict__ W1, const float* __restrict__ b1,
    const float* __restrict__ W2, const float* __restrict__ b2,
    const float* __restrict__ W3, const float* __restrict__ b3,
    const float* __restrict__ Wo, const float* __restrict__ bo_,
    float* __restrict__ zk_out) {
  __shared__ __align__(16) float hb[2][8][512];
  __shared__ __align__(16) float xb[8][32];
  const int t = threadIdx.x;
  const int row0 = blockIdx.x * 8;
  if (t < 256) {
    int r = t >> 5, j = t & 31;
    float v = xk[(size_t)(row0 + r) * 32 + j];
    xb[r][j] = v;
    zk_out[(size_t)(row0 + r) * 128 + j] = v;      // x pass-through
  }
  __syncthreads();
  const int c = t;
  // layer 1: K=32
  {
    float a[8];
    const float i0 = b1[c];
    #pragma unroll
    for (int r = 0; r < 8; ++r) a[r] = i0;
    for (int k = 0; k < 32; k += 4) {
      float w0 = W1[(size_t)(k+0)*512 + c];
      float w1 = W1[(size_t)(k+1)*512 + c];
      float w2 = W1[(size_t)(k+2)*512 + c];
      float w3 = W1[(size_t)(k+3)*512 + c];
      #pragma unroll
      for (int r = 0; r < 8; ++r) {
        f32x4 z = *(const f32x4*)&xb[r][k];
        a[r] += z[0]*w0 + z[1]*w1 + z[2]*w2 + z[3]*w3;
      }
    }
    #pragma unroll
    for (int r = 0; r < 8; ++r) hb[0][r][c] = fmaxf(a[r], 0.f);
  }
  __syncthreads();
  // layers 2,3: K=512
  #pragma unroll
  for (int lyr = 0; lyr < 2; ++lyr) {
    const float* W = lyr ? W3 : W2;
    const float* bb = lyr ? b3 : b2;
    const float (*hin)[512] = hb[lyr & 1];
    float (*hout)[512] = hb[(lyr & 1) ^ 1];
    float a[8];
    const float i0 = bb[c];
    #pragma unroll
    for (int r = 0; r < 8; ++r) a[r] = i0;
    for (int k = 0; k < 512; k += 4) {
      float w0 = W[(size_t)(k+0)*512 + c];
      float w1 = W[(size_t)(k+1)*512 + c];
      float w2 = W[(size_t)(k+2)*512 + c];
      float w3 = W[(size_t)(k+3)*512 + c];
      #pragma unroll
      for (int r = 0; r < 8; ++r) {
        f32x4 z = *(const f32x4*)&hin[r][k];
        a[r] += z[0]*w0 + z[1]*w1 + z[2]*w2 + z[3]*w3;
      }
    }
    #pragma unroll
    for (int r = 0; r < 8; ++r) hout[r][c] = fmaxf(a[r], 0.f);
    __syncthreads();
  }
  // output layer: N=96
  if (t < 96) {
    float a[8];
    const float i0 = bo_[t];
    #pragma unroll
    for (int r = 0; r < 8; ++r) a[r] = i0;
    for (int k = 0; k < 512; k += 4) {
      float w0 = Wo[(size_t)(k+0)*96 + t];
      float w1 = Wo[(size_t)(k+1)*96 + t];
      float w2 = Wo[(size_t)(k+2)*96 + t];
      float w3 = Wo[(size_t)(k+3)*96 + t];
      #pragma unroll
      for (int r = 0; r < 8; ++r) {
        f32x4 z = *(const f32x4*)&hb[0][r][k];
        a[r] += z[0]*w0 + z[1]*w1 + z[2]*w2 + z[3]*w3;
      }
    }
    #pragma unroll
    for (int r = 0; r < 8; ++r)
      zk_out[(size_t)(row0 + r) * 128 + 32 + t] = a[r];
  }
}

// ---------------------------------------------------------------------------
// Scan — hi/lo bf16 MFMA (fp32 emulation): z_{s+1} = z_s @ A + u_s @ Bmat.
// R8: block = 8 rows, 512 thr (8 waves, 1 coltile each -> 2 waves/SIMD, was
// 1) and 3 independent MFMA partial chains (len 4, was one len-12 chain).
// Error ~1e-5/step (bf16 x bf16 products exact in fp32).
// ---------------------------------------------------------------------------
__global__ __launch_bounds__(512) void scan_mfma(
    const float* __restrict__ zk, const u16* __restrict__ wf,
    const float* __restrict__ Bm, const float* __restrict__ useq,
    float* __restrict__ zpred, float* __restrict__ xpred) {
  __shared__ __align__(16) u16 ahf[32 * 512];     // 32KB A-hi frags
  __shared__ __align__(16) u16 alf[32 * 512];     // 32KB A-lo frags
  __shared__ __align__(16) float ubuf[8 * 512];   // 16KB u (rows x steps x 8)
  __shared__ __align__(16) float zbuf[8][132];    // current z (fp32, padded)
  __shared__ __align__(16) u16 zh[16][136];       // z hi bf16 (padded)
  __shared__ __align__(16) u16 zl[16][136];       // z lo bf16
  __shared__ __align__(16) float bu[8][132];      // u@B for this step
  const int t = threadIdx.x;
  const int wv = t >> 6, l = t & 63;
  const int q = l >> 4, n = l & 15;
  const size_t b0 = (size_t)blockIdx.x * 8;

  // async stage Ah/Al (wave wv: frags wv*4 .. wv*4+4 of each)
  #pragma unroll
  for (int i = 0; i < 4; ++i) {
    const int f = wv * 4 + i;
    __builtin_amdgcn_global_load_lds(
        (const __attribute__((address_space(1))) unsigned int*)(wf + OFF_AH + (size_t)f * 512 + l * 8),
        (__attribute__((address_space(3))) unsigned int*)(ahf + (size_t)f * 512), 16, 0, 0);
    __builtin_amdgcn_global_load_lds(
        (const __attribute__((address_space(1))) unsigned int*)(wf + OFF_AL + (size_t)f * 512 + l * 8),
        (__attribute__((address_space(3))) unsigned int*)(alf + (size_t)f * 512), 16, 0, 0);
  }
  // stage u (16KB contiguous)
  {
    const float* us = useq + b0 * 512;
    *(f32x4*)&ubuf[t * 8]     = *(const f32x4*)(us + t * 8);
    *(f32x4*)&ubuf[t * 8 + 4] = *(const f32x4*)(us + t * 8 + 4);
  }
  // z0; zero the garbage rows 8..15 of zh/zl (MFMA reads them)
  if (t < 256) {
    const int r = t >> 5, c4 = (t & 31) * 4;
    *(f32x4*)&zbuf[r][c4] = *(const f32x4*)(zk + (b0 + r) * 128 + c4);
  }
  for (int i = t; i < 8 * 136; i += 512) { (&zh[8][0])[i] = 0; (&zl[8][0])[i] = 0; }
  // B columns for bu: thread owns (row=wv, cols 2l, 2l+1)
  float bm0[8], bm1[8];
  #pragma unroll
  for (int j = 0; j < 8; ++j) {
    bm0[j] = Bm[(size_t)j * 128 + 2 * l];
    bm1[j] = Bm[(size_t)j * 128 + 2 * l + 1];
  }
  __syncthreads();

  for (int s = 0; s < 64; ++s) {
    // ---- conv + bu (thread: row=wv, cols 2l, 2l+1) ----
    {
      float z0 = zbuf[wv][2 * l], z1 = zbuf[wv][2 * l + 1];
      u16 h0 = f2bf(z0), h1 = f2bf(z1);
      u16 lo0 = f2bf(z0 - bf2f(h0)), lo1 = f2bf(z1 - bf2f(h1));
      *(unsigned int*)&zh[wv][2 * l] = (unsigned int)h0 | ((unsigned int)h1 << 16);
      *(unsigned int*)&zl[wv][2 * l] = (unsigned int)lo0 | ((unsigned int)lo1 << 16);
      f32x4 ua = *(const f32x4*)&ubuf[wv * 512 + s * 8];
      f32x4 ub = *(const f32x4*)&ubuf[wv * 512 + s * 8 + 4];
      float bv0 = ua[0]*bm0[0] + ua[1]*bm0[1] + ua[2]*bm0[2] + ua[3]*bm0[3]
                + ub[0]*bm0[4] + ub[1]*bm0[5] + ub[2]*bm0[6] + ub[3]*bm0[7];
      float bv1 = ua[0]*bm1[0] + ua[1]*bm1[1] + ua[2]*bm1[2] + ua[3]*bm1[3]
                + ub[0]*bm1[4] + ub[1]*bm1[5] + ub[2]*bm1[6] + ub[3]*bm1[7];
      bu[wv][2 * l]     = bv0;
      bu[wv][2 * l + 1] = bv1;
    }
    __syncthreads();
    // ---- MFMA: wave wv -> out-cols [wv*16, wv*16+16), 3 independent chains
    f32x4 aH = {0.f, 0.f, 0.f, 0.f};
    f32x4 aL = {0.f, 0.f, 0.f, 0.f};
    f32x4 aM = {0.f, 0.f, 0.f, 0.f};
    #pragma unroll
    for (int ks = 0; ks < 4; ++ks) {
      const int ko = ks * 32 + q * 8;
      bf16x8 azh = *(const bf16x8*)&zh[n][ko];     // A: row=lane&15, k=(lane>>4)*8+j
      bf16x8 azl = *(const bf16x8*)&zl[n][ko];
      bf16x8 bh = *(const bf16x8*)&ahf[(size_t)(wv * 4 + ks) * 512 + l * 8];
      bf16x8 bl = *(const bf16x8*)&alf[(size_t)(wv * 4 + ks) * 512 + l * 8];
      aH = __builtin_amdgcn_mfma_f32_16x16x32_bf16(azh, bh, aH, 0, 0, 0);
      aL = __builtin_amdgcn_mfma_f32_16x16x32_bf16(azl, bh, aL, 0, 0, 0);
      aM = __builtin_amdgcn_mfma_f32_16x16x32_bf16(azh, bl, aM, 0, 0, 0);
    }
    f32x4 acc = aH + aL;
    acc = acc + aM;
    // ---- epilogue: rows 0..7 live in q<2 lanes (C: col=lane&15, row=q*4+r)
    if (q < 2) {
      #pragma unroll
      for (int r = 0; r < 4; ++r) {
        const int row = q * 4 + r;
        const int c = wv * 16 + n;
        const float v = acc[r] + bu[row][c];
        zbuf[row][c] = v;
        const size_t go = (b0 + row) * 64 + s;
        zpred[go * 128 + c] = v;
        if (wv < 2) xpred[go * 32 + c] = v;   // cols 0..31 = x_pred
      }
    }
    __syncthreads();
  }
}

// ---------------------------------------------------------------------------
extern "C" void kernel_launch(void* const* d_in, const int* in_sizes, int n_in,
                              void* d_out, int out_size, void* d_ws, size_t ws_size,
                              hipStream_t stream) {
  (void)in_sizes; (void)n_in; (void)out_size; (void)ws_size;
  const float* xk    = (const float*)d_in[0];
  const float* useq  = (const float*)d_in[1];
  const float* xnext = (const float*)d_in[2];
  const float* W1 = (const float*)d_in[3];
  const float* b1 = (const float*)d_in[4];
  const float* W2 = (const float*)d_in[5];
  const float* b2 = (const float*)d_in[6];
  const float* W3 = (const float*)d_in[7];
  const float* b3 = (const float*)d_in[8];
  const float* Wo = (const float*)d_in[9];
  const float* bo = (const float*)d_in[10];
  const float* A  = (const float*)d_in[11];
  const float* Bm = (const float*)d_in[12];

  float* out   = (float*)d_out;
  float* zpred = out;
  float* xpred = out + XPRED_OFF;
  float* ztgt  = out + ZTGT_OFF;
  u16*   wf    = (u16*)d_ws;
  float* zkw   = (float*)((char*)d_ws + OFF_ZK_BYTES);

  prep_swizzle<<<1216, 64, 0, stream>>>(W1, W2, W3, Wo, A, wf);
  encoder_zk_f32<<<256, 512, 0, stream>>>(xk, W1, b1, W2, b2, W3, b3, Wo, bo, zkw);
  scan_mfma<<<256, 512, 0, stream>>>(zkw, wf, Bm, useq, zpred, xpred);
  encoder_tgt<<<1024, 512, 0, stream>>>(xnext, wf, b1, b2, b3, bo, ztgt);
}